// Round 1
// baseline (279.078 us; speedup 1.0000x reference)
//
#include <hip/hip_runtime.h>
#include <hip/hip_bf16.h>
#include <cstdint>
#include <cstddef>

#define P_ 256
#define L_ 6
#define D_ 300
#define J_ 3072   // P*2*L
#define N_ 4096
#define H_ 256
#define C_ 5
#define NCH 256   // time chunks (pass 1)
#define CS 16     // steps per chunk: NCH*CS == N_
#define NSUP 32   // superchunks (after level-1 compose)
#define SUBS 8    // chunks composed per level-1 worker

#define SLS 0.62245933120185459f  // sigmoid(0.5)

__device__ __forceinline__ float sigmoidf_(float x) { return 1.0f / (1.0f + __expf(-x)); }

// ---------------------------------------------------------------------------
// Kernel 1: T[n][j] = sigmoid(emb[doc[n]] . diags[j] + bias[j])
// fp32 tiled GEMM, 64x64 tile, BK=16, 256 threads, 4x4 microtile.
// ---------------------------------------------------------------------------
__global__ __launch_bounds__(256) void gemm_sigmoid(
    const int* __restrict__ doc, const float* __restrict__ emb,
    const float* __restrict__ diags, const float* __restrict__ bias,
    float* __restrict__ T)
{
    __shared__ float As[64][17];
    __shared__ float Bs[64][17];
    __shared__ int rowIdx[64];

    const int tid = threadIdx.x;
    const int m0 = blockIdx.y * 64;   // doc-position tile
    const int j0 = blockIdx.x * 64;   // pattern-feature tile

    if (tid < 64) rowIdx[tid] = doc[m0 + tid];
    __syncthreads();

    const int tx = tid & 15, ty = tid >> 4;
    float acc[4][4] = {};

    for (int kt = 0; kt < 19; ++kt) {   // 19*16 = 304 >= 300 (guarded)
        const int k0 = kt * 16;
        #pragma unroll
        for (int i = 0; i < 4; ++i) {
            int e = tid + i * 256;
            int m = e >> 4, k = e & 15;
            int gk = k0 + k;
            As[m][k] = (gk < D_) ? emb[(size_t)rowIdx[m] * D_ + gk] : 0.0f;
            Bs[m][k] = (gk < D_) ? diags[(size_t)(j0 + m) * D_ + gk] : 0.0f;
        }
        __syncthreads();
        #pragma unroll
        for (int k = 0; k < 16; ++k) {
            float a[4], b[4];
            #pragma unroll
            for (int i = 0; i < 4; ++i) a[i] = As[ty + 16 * i][k];
            #pragma unroll
            for (int i = 0; i < 4; ++i) b[i] = Bs[tx + 16 * i][k];
            #pragma unroll
            for (int i = 0; i < 4; ++i)
                #pragma unroll
                for (int j = 0; j < 4; ++j)
                    acc[i][j] = fmaf(a[i], b[j], acc[i][j]);
        }
        __syncthreads();
    }

    #pragma unroll
    for (int i = 0; i < 4; ++i) {
        const int gm = m0 + ty + 16 * i;
        #pragma unroll
        for (int j = 0; j < 4; ++j) {
            const int gj = j0 + tx + 16 * j;
            float v = acc[i][j] + bias[gj];
            T[(size_t)gm * J_ + gj] = sigmoidf_(v);
        }
    }
}

// ---------------------------------------------------------------------------
// Kernel 2: per (chunk c, pattern p) compute the affine map of CS steps on the
// augmented state u = (h[0..5], s).  7 basis columns (6 h-basis + const).
// Output G[(c*49 + col*7 + comp)*256 + p], comp 0..5 = h, comp 6 = s.
// ---------------------------------------------------------------------------
__global__ __launch_bounds__(256) void scan_pass1(
    const float* __restrict__ T, const float* __restrict__ epsilon,
    float* __restrict__ G)
{
    const int c = blockIdx.x;     // chunk
    const int p = threadIdx.x;    // pattern

    float ep[5];
    #pragma unroll
    for (int l = 0; l < 5; ++l)
        ep[l] = SLS * (1.0f / (1.0f + __expf(-epsilon[p * 5 + l])));

    float hc[7][6];
    float sc[7];
    #pragma unroll
    for (int j = 0; j < 7; ++j) {
        sc[j] = 0.0f;
        #pragma unroll
        for (int i = 0; i < 6; ++i) hc[j][i] = (i == j) ? 1.0f : 0.0f;
    }

    const int t0 = c * CS;
    for (int t = t0; t < t0 + CS; ++t) {
        const float4* tp = (const float4*)(T + (size_t)t * J_ + p * 12);
        float4 v0 = tp[0], v1 = tp[1], v2 = tp[2];
        float T0[6] = {v0.x, v0.y, v0.z, v0.w, v1.x, v1.y};
        float T1[6] = {v1.z, v1.w, v2.x, v2.y, v2.z, v2.w};
        float sT0[6];
        #pragma unroll
        for (int l = 0; l < 6; ++l) sT0[l] = SLS * T0[l];

        #pragma unroll
        for (int j = 0; j < 7; ++j) {
            float m[6];
            m[0] = hc[j][0] * sT0[0];
            #pragma unroll
            for (int i = 1; i < 6; ++i)
                m[i] = fmaf(hc[j][i - 1], T1[i - 1], hc[j][i] * sT0[i]);
            hc[j][0] = m[0] + ((j == 6) ? 1.0f : 0.0f);
            #pragma unroll
            for (int i = 1; i < 6; ++i)
                hc[j][i] = fmaf(m[i - 1], ep[i - 1], m[i]);
            sc[j] += hc[j][5];
        }
    }

    #pragma unroll
    for (int j = 0; j < 7; ++j) {
        #pragma unroll
        for (int i = 0; i < 6; ++i)
            G[((size_t)c * 49 + j * 7 + i) * P_ + p] = hc[j][i];
        G[((size_t)c * 49 + j * 7 + 6) * P_ + p] = sc[j];
    }
}

// ---------------------------------------------------------------------------
// Kernel 3: compose SUBS=8 consecutive chunk maps -> NSUP=32 superchunk maps.
// grid 128 blocks x 64 threads: block -> (g = bid>>2, psub = bid&3).
// ---------------------------------------------------------------------------
__global__ __launch_bounds__(64) void compose_l1(
    const float* __restrict__ G, float* __restrict__ G2)
{
    const int g = blockIdx.x >> 2;
    const int p = (blockIdx.x & 3) * 64 + threadIdx.x;

    float Rh[7][6], Rs[7];
    #pragma unroll
    for (int j = 0; j < 7; ++j) {
        Rs[j] = 0.0f;
        #pragma unroll
        for (int i = 0; i < 6; ++i) Rh[j][i] = (i == j) ? 1.0f : 0.0f;
    }

    for (int cc = 0; cc < SUBS; ++cc) {
        const int c = g * SUBS + cc;
        float Ch[7][6], Csv[7];
        #pragma unroll
        for (int j = 0; j < 7; ++j) {
            #pragma unroll
            for (int i = 0; i < 6; ++i)
                Ch[j][i] = G[((size_t)c * 49 + j * 7 + i) * P_ + p];
            Csv[j] = G[((size_t)c * 49 + j * 7 + 6) * P_ + p];
        }
        // R = C o R
        float Nh[7][6], Ns[7];
        #pragma unroll
        for (int j = 0; j < 7; ++j) {
            #pragma unroll
            for (int i = 0; i < 6; ++i) {
                float a = (j == 6) ? Ch[6][i] : 0.0f;
                #pragma unroll
                for (int u = 0; u < 6; ++u) a = fmaf(Ch[u][i], Rh[j][u], a);
                Nh[j][i] = a;
            }
            float sa = Rs[j] + ((j == 6) ? Csv[6] : 0.0f);
            #pragma unroll
            for (int u = 0; u < 6; ++u) sa = fmaf(Csv[u], Rh[j][u], sa);
            Ns[j] = sa;
        }
        #pragma unroll
        for (int j = 0; j < 7; ++j) {
            Rs[j] = Ns[j];
            #pragma unroll
            for (int i = 0; i < 6; ++i) Rh[j][i] = Nh[j][i];
        }
    }

    #pragma unroll
    for (int j = 0; j < 7; ++j) {
        #pragma unroll
        for (int i = 0; i < 6; ++i)
            G2[((size_t)g * 49 + j * 7 + i) * P_ + p] = Rh[j][i];
        G2[((size_t)g * 49 + j * 7 + 6) * P_ + p] = Rs[j];
    }
}

// ---------------------------------------------------------------------------
// Kernel 4: apply the NSUP superchunk maps in order to (h0, s=0) -> scores[p].
// grid 4 blocks x 64 threads.
// ---------------------------------------------------------------------------
__global__ __launch_bounds__(64) void compose_l2(
    const float* __restrict__ G2, float* __restrict__ scores)
{
    const int p = blockIdx.x * 64 + threadIdx.x;
    float h[6] = {1.0f, 0.0f, 0.0f, 0.0f, 0.0f, 0.0f};
    float s = 0.0f;

    for (int g = 0; g < NSUP; ++g) {
        float Ch[7][6], Csv[7];
        #pragma unroll
        for (int j = 0; j < 7; ++j) {
            #pragma unroll
            for (int i = 0; i < 6; ++i)
                Ch[j][i] = G2[((size_t)g * 49 + j * 7 + i) * P_ + p];
            Csv[j] = G2[((size_t)g * 49 + j * 7 + 6) * P_ + p];
        }
        float nh[6];
        #pragma unroll
        for (int i = 0; i < 6; ++i) {
            float a = Ch[6][i];
            #pragma unroll
            for (int u = 0; u < 6; ++u) a = fmaf(Ch[u][i], h[u], a);
            nh[i] = a;
        }
        float ns = s + Csv[6];
        #pragma unroll
        for (int u = 0; u < 6; ++u) ns = fmaf(Csv[u], h[u], ns);
        #pragma unroll
        for (int i = 0; i < 6; ++i) h[i] = nh[i];
        s = ns;
    }
    scores[p] = s;
}

// ---------------------------------------------------------------------------
// Kernel 5: tiny MLP head. One block, 256 threads.
// ---------------------------------------------------------------------------
__global__ __launch_bounds__(256) void mlp_head(
    const float* __restrict__ scores,
    const float* __restrict__ w0, const float* __restrict__ b0,
    const float* __restrict__ w1, const float* __restrict__ b1,
    const float* __restrict__ w2, const float* __restrict__ b2,
    float* __restrict__ out)
{
    __shared__ float s0[H_], z0[H_], z1[H_];
    const int tid = threadIdx.x;

    s0[tid] = scores[tid];
    __syncthreads();

    float acc = b0[tid];
    {
        const float4* wr = (const float4*)(w0 + (size_t)tid * P_);
        #pragma unroll 4
        for (int q = 0; q < P_ / 4; ++q) {
            float4 w = wr[q];
            acc = fmaf(w.x, s0[q * 4 + 0], acc);
            acc = fmaf(w.y, s0[q * 4 + 1], acc);
            acc = fmaf(w.z, s0[q * 4 + 2], acc);
            acc = fmaf(w.w, s0[q * 4 + 3], acc);
        }
    }
    z0[tid] = fmaxf(acc, 0.0f);
    __syncthreads();

    acc = b1[tid];
    {
        const float4* wr = (const float4*)(w1 + (size_t)tid * H_);
        #pragma unroll 4
        for (int q = 0; q < H_ / 4; ++q) {
            float4 w = wr[q];
            acc = fmaf(w.x, z0[q * 4 + 0], acc);
            acc = fmaf(w.y, z0[q * 4 + 1], acc);
            acc = fmaf(w.z, z0[q * 4 + 2], acc);
            acc = fmaf(w.w, z0[q * 4 + 3], acc);
        }
    }
    z1[tid] = fmaxf(acc, 0.0f);
    __syncthreads();

    if (tid < C_) {
        float o = b2[tid];
        const float* wr = w2 + (size_t)tid * H_;
        for (int h = 0; h < H_; ++h) o = fmaf(wr[h], z1[h], o);
        out[tid] = o;
    }
}

// ---------------------------------------------------------------------------
extern "C" void kernel_launch(void* const* d_in, const int* in_sizes, int n_in,
                              void* d_out, int out_size, void* d_ws, size_t ws_size,
                              hipStream_t stream)
{
    const int*   doc     = (const int*)d_in[0];
    const float* emb     = (const float*)d_in[1];
    const float* diags   = (const float*)d_in[2];
    const float* bias    = (const float*)d_in[3];
    const float* epsilon = (const float*)d_in[4];
    const float* w0      = (const float*)d_in[5];
    const float* b0      = (const float*)d_in[6];
    const float* w1      = (const float*)d_in[7];
    const float* b1      = (const float*)d_in[8];
    const float* w2      = (const float*)d_in[9];
    const float* b2      = (const float*)d_in[10];
    float* out = (float*)d_out;

    float* T      = (float*)d_ws;                         // N_*J_            (50.3 MB)
    float* G      = T + (size_t)N_ * J_;                  // NCH*49*P_        (3.2 MB)
    float* G2     = G + (size_t)NCH * 49 * P_;            // NSUP*49*P_       (0.4 MB)
    float* scores = G2 + (size_t)NSUP * 49 * P_;          // P_

    dim3 gemm_grid(J_ / 64, N_ / 64);   // (48, 64)
    gemm_sigmoid<<<gemm_grid, 256, 0, stream>>>(doc, emb, diags, bias, T);
    scan_pass1<<<NCH, 256, 0, stream>>>(T, epsilon, G);
    compose_l1<<<128, 64, 0, stream>>>(G, G2);
    compose_l2<<<4, 64, 0, stream>>>(G2, scores);
    mlp_head<<<1, 256, 0, stream>>>(scores, w0, b0, w1, b1, w2, b2, out);
}

// Round 2
// 110.512 us; speedup vs baseline: 2.5253x; 2.5253x over previous
//
#include <hip/hip_runtime.h>
#include <hip/hip_bf16.h>
#include <cstdint>
#include <cstddef>

#define P_ 256
#define L_ 6
#define D_ 300
#define J_ 3072   // P*2*L
#define N_ 4096
#define H_ 256
#define C_ 5
#define KP 320    // K padded to multiple of 32
#define KSTEPS 10 // KP/32
#define NCH 256   // time chunks (pass 1)
#define CS 16     // steps per chunk: NCH*CS == N_
#define NSUP 32   // superchunks (after level-1 compose)
#define SUBS 8    // chunks composed per level-1 worker

#define SLS 0.62245933120185459f  // sigmoid(0.5)

typedef __attribute__((ext_vector_type(8))) short short8v;  // 8 bf16 (4 VGPRs)
typedef __attribute__((ext_vector_type(4))) float f32x4;

__device__ __forceinline__ float sigmoidf_(float x) { return 1.0f / (1.0f + __expf(-x)); }

// ---------------------------------------------------------------------------
// Prep: gather emb[doc] -> X bf16 [N_][KP], zero-padded cols 300..319
// ---------------------------------------------------------------------------
__global__ __launch_bounds__(256) void prep_X(
    const int* __restrict__ doc, const float* __restrict__ emb,
    __hip_bfloat16* __restrict__ X)
{
    const int i = blockIdx.x * 256 + threadIdx.x;   // over N_*KP
    const int n = i / KP, k = i - n * KP;
    float v = (k < D_) ? emb[(size_t)doc[n] * D_ + k] : 0.0f;
    X[i] = __float2bfloat16(v);
}

// Prep: diags -> Bb bf16 [J_][KP], zero-padded
__global__ __launch_bounds__(256) void prep_B(
    const float* __restrict__ diags, __hip_bfloat16* __restrict__ Bb)
{
    const int i = blockIdx.x * 256 + threadIdx.x;   // over J_*KP
    const int j = i / KP, k = i - j * KP;
    float v = (k < D_) ? diags[(size_t)j * D_ + k] : 0.0f;
    Bb[i] = __float2bfloat16(v);
}

// ---------------------------------------------------------------------------
// Kernel 1: T = sigmoid(X @ Bb^T + bias), bf16 MFMA (m97 structure).
// 128x128 tile, 4 waves (2x2), each wave 64x64 = 4x4 frags of 16x16x32.
// global_load_lds width-16 staging, single-buffered 2-barrier K-loop.
// ---------------------------------------------------------------------------
__global__ __launch_bounds__(256) void gemm_mfma(
    const __hip_bfloat16* __restrict__ X, const __hip_bfloat16* __restrict__ Bb,
    const float* __restrict__ bias, float* __restrict__ T)
{
    __shared__ __hip_bfloat16 As[128 * 32];
    __shared__ __hip_bfloat16 Bs[128 * 32];

    const int tid  = threadIdx.x;
    const int lane = tid & 63;
    const int w    = tid >> 6;          // wave 0..3
    const int wr   = w >> 1, wc = w & 1;
    const int m0   = blockIdx.y * 128;
    const int j0   = blockIdx.x * 128;

    // staging geometry: chunk = w*2+q covers LDS bytes [chunk*1024, +1024)
    // lane l -> elem chunk*512 + l*8 -> row chunk*16 + l/4, col (l&3)*8
    const int srow = w * 32 + (lane >> 2);   // + q*16
    const int scol = (lane & 3) * 8;

    f32x4 acc[4][4];
    #pragma unroll
    for (int m = 0; m < 4; ++m)
        #pragma unroll
        for (int n = 0; n < 4; ++n)
            acc[m][n] = (f32x4){0.f, 0.f, 0.f, 0.f};

    const int fr = lane & 15;            // fragment row/col within 16
    const int kg = (lane >> 4) * 8;      // fragment k-offset (elements)

    for (int kt = 0; kt < KSTEPS; ++kt) {
        const int k0 = kt * 32;
        #pragma unroll
        for (int q = 0; q < 2; ++q) {
            const __hip_bfloat16* ga = X + (size_t)(m0 + srow + q * 16) * KP + k0 + scol;
            __builtin_amdgcn_global_load_lds(
                (const __attribute__((address_space(1))) unsigned*)ga,
                (__attribute__((address_space(3))) unsigned*)(As + (w * 2 + q) * 512),
                16, 0, 0);
            const __hip_bfloat16* gb = Bb + (size_t)(j0 + srow + q * 16) * KP + k0 + scol;
            __builtin_amdgcn_global_load_lds(
                (const __attribute__((address_space(1))) unsigned*)gb,
                (__attribute__((address_space(3))) unsigned*)(Bs + (w * 2 + q) * 512),
                16, 0, 0);
        }
        __syncthreads();   // compiler drains vmcnt before barrier

        short8v a[4], b[4];
        #pragma unroll
        for (int m = 0; m < 4; ++m)
            a[m] = *(const short8v*)(As + (wr * 64 + m * 16 + fr) * 32 + kg);
        #pragma unroll
        for (int n = 0; n < 4; ++n)
            b[n] = *(const short8v*)(Bs + (wc * 64 + n * 16 + fr) * 32 + kg);
        #pragma unroll
        for (int m = 0; m < 4; ++m)
            #pragma unroll
            for (int n = 0; n < 4; ++n)
                acc[m][n] = __builtin_amdgcn_mfma_f32_16x16x32_bf16(a[m], b[n], acc[m][n], 0, 0, 0);
        __syncthreads();
    }

    // epilogue: C/D mapping col=lane&15, row=(lane>>4)*4+reg  [m89-verified]
    #pragma unroll
    for (int n = 0; n < 4; ++n) {
        const int j = j0 + wc * 64 + n * 16 + fr;
        const float bj = bias[j];
        #pragma unroll
        for (int m = 0; m < 4; ++m) {
            const int rbase = m0 + wr * 64 + m * 16 + (lane >> 4) * 4;
            #pragma unroll
            for (int r = 0; r < 4; ++r) {
                float v = acc[m][n][r] + bj;
                T[(size_t)(rbase + r) * J_ + j] = sigmoidf_(v);
            }
        }
    }
}

// ---------------------------------------------------------------------------
// Kernel 2: per (chunk c, pattern p) affine map of CS steps on u=(h[6], s).
// ---------------------------------------------------------------------------
__global__ __launch_bounds__(256) void scan_pass1(
    const float* __restrict__ T, const float* __restrict__ epsilon,
    float* __restrict__ G)
{
    const int c = blockIdx.x;
    const int p = threadIdx.x;

    float ep[5];
    #pragma unroll
    for (int l = 0; l < 5; ++l)
        ep[l] = SLS * (1.0f / (1.0f + __expf(-epsilon[p * 5 + l])));

    float hc[7][6];
    float sc[7];
    #pragma unroll
    for (int j = 0; j < 7; ++j) {
        sc[j] = 0.0f;
        #pragma unroll
        for (int i = 0; i < 6; ++i) hc[j][i] = (i == j) ? 1.0f : 0.0f;
    }

    const int t0 = c * CS;
    for (int t = t0; t < t0 + CS; ++t) {
        const float4* tp = (const float4*)(T + (size_t)t * J_ + p * 12);
        float4 v0 = tp[0], v1 = tp[1], v2 = tp[2];
        float T0[6] = {v0.x, v0.y, v0.z, v0.w, v1.x, v1.y};
        float T1[6] = {v1.z, v1.w, v2.x, v2.y, v2.z, v2.w};
        float sT0[6];
        #pragma unroll
        for (int l = 0; l < 6; ++l) sT0[l] = SLS * T0[l];

        #pragma unroll
        for (int j = 0; j < 7; ++j) {
            float m[6];
            m[0] = hc[j][0] * sT0[0];
            #pragma unroll
            for (int i = 1; i < 6; ++i)
                m[i] = fmaf(hc[j][i - 1], T1[i - 1], hc[j][i] * sT0[i]);
            hc[j][0] = m[0] + ((j == 6) ? 1.0f : 0.0f);
            #pragma unroll
            for (int i = 1; i < 6; ++i)
                hc[j][i] = fmaf(m[i - 1], ep[i - 1], m[i]);
            sc[j] += hc[j][5];
        }
    }

    #pragma unroll
    for (int j = 0; j < 7; ++j) {
        #pragma unroll
        for (int i = 0; i < 6; ++i)
            G[((size_t)c * 49 + j * 7 + i) * P_ + p] = hc[j][i];
        G[((size_t)c * 49 + j * 7 + 6) * P_ + p] = sc[j];
    }
}

// ---------------------------------------------------------------------------
// Kernel 3: compose SUBS=8 chunk maps -> NSUP=32 superchunk maps.
// ---------------------------------------------------------------------------
__global__ __launch_bounds__(64) void compose_l1(
    const float* __restrict__ G, float* __restrict__ G2)
{
    const int g = blockIdx.x >> 2;
    const int p = (blockIdx.x & 3) * 64 + threadIdx.x;

    float Rh[7][6], Rs[7];
    #pragma unroll
    for (int j = 0; j < 7; ++j) {
        Rs[j] = 0.0f;
        #pragma unroll
        for (int i = 0; i < 6; ++i) Rh[j][i] = (i == j) ? 1.0f : 0.0f;
    }

    for (int cc = 0; cc < SUBS; ++cc) {
        const int c = g * SUBS + cc;
        float Ch[7][6], Csv[7];
        #pragma unroll
        for (int j = 0; j < 7; ++j) {
            #pragma unroll
            for (int i = 0; i < 6; ++i)
                Ch[j][i] = G[((size_t)c * 49 + j * 7 + i) * P_ + p];
            Csv[j] = G[((size_t)c * 49 + j * 7 + 6) * P_ + p];
        }
        float Nh[7][6], Ns[7];
        #pragma unroll
        for (int j = 0; j < 7; ++j) {
            #pragma unroll
            for (int i = 0; i < 6; ++i) {
                float a = (j == 6) ? Ch[6][i] : 0.0f;
                #pragma unroll
                for (int u = 0; u < 6; ++u) a = fmaf(Ch[u][i], Rh[j][u], a);
                Nh[j][i] = a;
            }
            float sa = Rs[j] + ((j == 6) ? Csv[6] : 0.0f);
            #pragma unroll
            for (int u = 0; u < 6; ++u) sa = fmaf(Csv[u], Rh[j][u], sa);
            Ns[j] = sa;
        }
        #pragma unroll
        for (int j = 0; j < 7; ++j) {
            Rs[j] = Ns[j];
            #pragma unroll
            for (int i = 0; i < 6; ++i) Rh[j][i] = Nh[j][i];
        }
    }

    #pragma unroll
    for (int j = 0; j < 7; ++j) {
        #pragma unroll
        for (int i = 0; i < 6; ++i)
            G2[((size_t)g * 49 + j * 7 + i) * P_ + p] = Rh[j][i];
        G2[((size_t)g * 49 + j * 7 + 6) * P_ + p] = Rs[j];
    }
}

// ---------------------------------------------------------------------------
// Kernel 4: apply NSUP superchunk maps in order to (h0, s=0) -> scores[p].
// ---------------------------------------------------------------------------
__global__ __launch_bounds__(64) void compose_l2(
    const float* __restrict__ G2, float* __restrict__ scores)
{
    const int p = blockIdx.x * 64 + threadIdx.x;
    float h[6] = {1.0f, 0.0f, 0.0f, 0.0f, 0.0f, 0.0f};
    float s = 0.0f;

    for (int g = 0; g < NSUP; ++g) {
        float Ch[7][6], Csv[7];
        #pragma unroll
        for (int j = 0; j < 7; ++j) {
            #pragma unroll
            for (int i = 0; i < 6; ++i)
                Ch[j][i] = G2[((size_t)g * 49 + j * 7 + i) * P_ + p];
            Csv[j] = G2[((size_t)g * 49 + j * 7 + 6) * P_ + p];
        }
        float nh[6];
        #pragma unroll
        for (int i = 0; i < 6; ++i) {
            float a = Ch[6][i];
            #pragma unroll
            for (int u = 0; u < 6; ++u) a = fmaf(Ch[u][i], h[u], a);
            nh[i] = a;
        }
        float ns = s + Csv[6];
        #pragma unroll
        for (int u = 0; u < 6; ++u) ns = fmaf(Csv[u], h[u], ns);
        #pragma unroll
        for (int i = 0; i < 6; ++i) h[i] = nh[i];
        s = ns;
    }
    scores[p] = s;
}

// ---------------------------------------------------------------------------
// Kernel 5: tiny MLP head. One block, 256 threads.
// ---------------------------------------------------------------------------
__global__ __launch_bounds__(256) void mlp_head(
    const float* __restrict__ scores,
    const float* __restrict__ w0, const float* __restrict__ b0,
    const float* __restrict__ w1, const float* __restrict__ b1,
    const float* __restrict__ w2, const float* __restrict__ b2,
    float* __restrict__ out)
{
    __shared__ float s0[H_], z0[H_], z1[H_];
    const int tid = threadIdx.x;

    s0[tid] = scores[tid];
    __syncthreads();

    float acc = b0[tid];
    {
        const float4* wr = (const float4*)(w0 + (size_t)tid * P_);
        #pragma unroll 4
        for (int q = 0; q < P_ / 4; ++q) {
            float4 w = wr[q];
            acc = fmaf(w.x, s0[q * 4 + 0], acc);
            acc = fmaf(w.y, s0[q * 4 + 1], acc);
            acc = fmaf(w.z, s0[q * 4 + 2], acc);
            acc = fmaf(w.w, s0[q * 4 + 3], acc);
        }
    }
    z0[tid] = fmaxf(acc, 0.0f);
    __syncthreads();

    acc = b1[tid];
    {
        const float4* wr = (const float4*)(w1 + (size_t)tid * H_);
        #pragma unroll 4
        for (int q = 0; q < H_ / 4; ++q) {
            float4 w = wr[q];
            acc = fmaf(w.x, z0[q * 4 + 0], acc);
            acc = fmaf(w.y, z0[q * 4 + 1], acc);
            acc = fmaf(w.z, z0[q * 4 + 2], acc);
            acc = fmaf(w.w, z0[q * 4 + 3], acc);
        }
    }
    z1[tid] = fmaxf(acc, 0.0f);
    __syncthreads();

    if (tid < C_) {
        float o = b2[tid];
        const float* wr = w2 + (size_t)tid * H_;
        for (int h = 0; h < H_; ++h) o = fmaf(wr[h], z1[h], o);
        out[tid] = o;
    }
}

// ---------------------------------------------------------------------------
extern "C" void kernel_launch(void* const* d_in, const int* in_sizes, int n_in,
                              void* d_out, int out_size, void* d_ws, size_t ws_size,
                              hipStream_t stream)
{
    const int*   doc     = (const int*)d_in[0];
    const float* emb     = (const float*)d_in[1];
    const float* diags   = (const float*)d_in[2];
    const float* bias    = (const float*)d_in[3];
    const float* epsilon = (const float*)d_in[4];
    const float* w0      = (const float*)d_in[5];
    const float* b0      = (const float*)d_in[6];
    const float* w1      = (const float*)d_in[7];
    const float* b1      = (const float*)d_in[8];
    const float* w2      = (const float*)d_in[9];
    const float* b2      = (const float*)d_in[10];
    float* out = (float*)d_out;

    // Workspace layout (same footprint as round 1):
    //   T  : N_*J_ fp32                       (50.33 MB)
    //   region2 = T_end:
    //     X  bf16 [N_][KP]  (2.62 MB)  \  overlaid: G (fp32, 12.85 MB) is
    //     Bb bf16 [J_][KP]  (1.97 MB)  /  written only AFTER gemm consumed X/Bb
    //   G2 : region2 + G_size (1.61 MB), scores after G2.
    float* T = (float*)d_ws;
    char*  region2 = (char*)(T + (size_t)N_ * J_);
    __hip_bfloat16* X  = (__hip_bfloat16*)region2;
    __hip_bfloat16* Bb = X + (size_t)N_ * KP;
    float* G      = (float*)region2;                       // overlays X/Bb
    float* G2     = G + (size_t)NCH * 49 * P_;
    float* scores = G2 + (size_t)NSUP * 49 * P_;

    prep_X<<<(N_ * KP) / 256, 256, 0, stream>>>(doc, emb, X);
    prep_B<<<(J_ * KP) / 256, 256, 0, stream>>>(diags, Bb);
    gemm_mfma<<<dim3(J_ / 128, N_ / 128), 256, 0, stream>>>(X, Bb, bias, T);
    scan_pass1<<<NCH, 256, 0, stream>>>(T, epsilon, G);
    compose_l1<<<128, 64, 0, stream>>>(G, G2);
    compose_l2<<<4, 64, 0, stream>>>(G2, scores);
    mlp_head<<<1, 256, 0, stream>>>(scores, w0, b0, w1, b1, w2, b2, out);
}

// Round 3
// 100.281 us; speedup vs baseline: 2.7830x; 1.1020x over previous
//
#include <hip/hip_runtime.h>
#include <hip/hip_bf16.h>
#include <cstdint>
#include <cstddef>

#define P_ 256
#define L_ 6
#define D_ 300
#define J_ 3072   // P*2*L
#define N_ 4096
#define H_ 256
#define C_ 5
#define KP 320    // K padded to multiple of 32
#define KSTEPS 10 // KP/32
#define NCH 512   // time chunks (pass 1)
#define CS 8      // steps per chunk: NCH*CS == N_
#define NL1 64    // after level-1 compose (512/8)
#define NL2 8     // after level-2 compose (64/8)

#define SLS 0.62245933120185459f  // sigmoid(0.5)

typedef __attribute__((ext_vector_type(8))) short short8v;  // 8 bf16 (4 VGPRs)
typedef __attribute__((ext_vector_type(4))) float f32x4;

__device__ __forceinline__ float sigmoidf_(float x) { return 1.0f / (1.0f + __expf(-x)); }
__device__ __forceinline__ float bl_(unsigned u) { return __uint_as_float(u << 16); }
__device__ __forceinline__ float bh_(unsigned u) { return __uint_as_float(u & 0xffff0000u); }

// ---------------------------------------------------------------------------
// Prep (fused): gather emb[doc] -> X bf16 [N_][KP]; diags -> Bb bf16 [J_][KP].
// Zero-padded cols 300..319.
// ---------------------------------------------------------------------------
__global__ __launch_bounds__(256) void prep_XB(
    const int* __restrict__ doc, const float* __restrict__ emb,
    const float* __restrict__ diags,
    __hip_bfloat16* __restrict__ X, __hip_bfloat16* __restrict__ Bb)
{
    const int i = blockIdx.x * 256 + threadIdx.x;
    const int NX = N_ * KP;
    if (i < NX) {
        const int n = i / KP, k = i - n * KP;
        float v = (k < D_) ? emb[(size_t)doc[n] * D_ + k] : 0.0f;
        X[i] = __float2bfloat16(v);
    } else {
        const int ii = i - NX;
        const int j = ii / KP, k = ii - j * KP;
        float v = (k < D_) ? diags[(size_t)j * D_ + k] : 0.0f;
        Bb[ii] = __float2bfloat16(v);
    }
}

// ---------------------------------------------------------------------------
// Kernel 1: T = sigmoid(X @ Bb^T + bias)  -> bf16 T.
// m97 structure + 2-phase prefetch: stage(kt+1) issued BEFORE compute(kt),
// loads fly under ds_read+MFMA, one drain per K-step (T3 minimum recipe).
// 128x128 tile, 4 waves (2x2), 4x4 frags of 16x16x32 each. XCD swizzle.
// ---------------------------------------------------------------------------
__global__ __launch_bounds__(256) void gemm_mfma(
    const __hip_bfloat16* __restrict__ X, const __hip_bfloat16* __restrict__ Bb,
    const float* __restrict__ bias, __hip_bfloat16* __restrict__ T)
{
    __shared__ __hip_bfloat16 As[2][128 * 32];
    __shared__ __hip_bfloat16 Bs[2][128 * 32];

    const int tid  = threadIdx.x;
    const int lane = tid & 63;
    const int w    = tid >> 6;          // wave 0..3
    const int wr   = w >> 1, wc = w & 1;

    // XCD-aware bijective swizzle: nwg = 768 = 8 * 96
    const int bid = blockIdx.x;
    const int swz = (bid & 7) * 96 + (bid >> 3);
    const int bx  = swz % 24, by = swz / 24;   // 24 j-tiles, 32 m-tiles
    const int m0  = by * 128;
    const int j0  = bx * 128;

    // staging: chunk = w*2+q covers LDS bytes [chunk*1024, +1024)
    const int srow = w * 32 + (lane >> 2);   // + q*16
    const int scol = (lane & 3) * 8;

    f32x4 acc[4][4];
    #pragma unroll
    for (int m = 0; m < 4; ++m)
        #pragma unroll
        for (int n = 0; n < 4; ++n)
            acc[m][n] = (f32x4){0.f, 0.f, 0.f, 0.f};

    const int fr = lane & 15;            // fragment row/col within 16
    const int kg = (lane >> 4) * 8;      // fragment k-offset (elements)

    auto stage = [&](int kt, int b) {
        const int k0 = kt * 32;
        #pragma unroll
        for (int q = 0; q < 2; ++q) {
            const __hip_bfloat16* ga = X + (size_t)(m0 + srow + q * 16) * KP + k0 + scol;
            __builtin_amdgcn_global_load_lds(
                (const __attribute__((address_space(1))) unsigned*)ga,
                (__attribute__((address_space(3))) unsigned*)(&As[b][(w * 2 + q) * 512]),
                16, 0, 0);
            const __hip_bfloat16* gb = Bb + (size_t)(j0 + srow + q * 16) * KP + k0 + scol;
            __builtin_amdgcn_global_load_lds(
                (const __attribute__((address_space(1))) unsigned*)gb,
                (__attribute__((address_space(3))) unsigned*)(&Bs[b][(w * 2 + q) * 512]),
                16, 0, 0);
        }
    };

    stage(0, 0);
    __syncthreads();   // drain prologue stage

    int buf = 0;
    for (int kt = 0; kt < KSTEPS; ++kt) {
        if (kt + 1 < KSTEPS) stage(kt + 1, buf ^ 1);   // prefetch next tile

        short8v a[4], b[4];
        #pragma unroll
        for (int m = 0; m < 4; ++m)
            a[m] = *(const short8v*)(&As[buf][(wr * 64 + m * 16 + fr) * 32 + kg]);
        #pragma unroll
        for (int n = 0; n < 4; ++n)
            b[n] = *(const short8v*)(&Bs[buf][(wc * 64 + n * 16 + fr) * 32 + kg]);
        #pragma unroll
        for (int m = 0; m < 4; ++m)
            #pragma unroll
            for (int n = 0; n < 4; ++n)
                acc[m][n] = __builtin_amdgcn_mfma_f32_16x16x32_bf16(a[m], b[n], acc[m][n], 0, 0, 0);

        __syncthreads();   // drains prefetch vmcnt + barrier (next tile ready)
        buf ^= 1;
    }

    // epilogue: C/D mapping col=lane&15, row=(lane>>4)*4+reg  [m89-verified]
    #pragma unroll
    for (int n = 0; n < 4; ++n) {
        const int j = j0 + wc * 64 + n * 16 + fr;
        const float bj = bias[j];
        #pragma unroll
        for (int m = 0; m < 4; ++m) {
            const int rbase = m0 + wr * 64 + m * 16 + (lane >> 4) * 4;
            #pragma unroll
            for (int r = 0; r < 4; ++r) {
                float v = acc[m][n][r] + bj;
                T[(size_t)(rbase + r) * J_ + j] = __float2bfloat16(sigmoidf_(v));
            }
        }
    }
}

// ---------------------------------------------------------------------------
// Kernel 2: per (chunk c, pattern p) affine map of CS steps on u=(h[6], s).
// bf16 T input. G[(c*49 + col*7 + comp)*256 + p].
// ---------------------------------------------------------------------------
__global__ __launch_bounds__(256) void scan_pass1(
    const __hip_bfloat16* __restrict__ Tb, const float* __restrict__ epsilon,
    float* __restrict__ G)
{
    const int c = blockIdx.x;
    const int p = threadIdx.x;

    float ep[5];
    #pragma unroll
    for (int l = 0; l < 5; ++l)
        ep[l] = SLS * (1.0f / (1.0f + __expf(-epsilon[p * 5 + l])));

    float hc[7][6];
    float sc[7];
    #pragma unroll
    for (int j = 0; j < 7; ++j) {
        sc[j] = 0.0f;
        #pragma unroll
        for (int i = 0; i < 6; ++i) hc[j][i] = (i == j) ? 1.0f : 0.0f;
    }

    const int t0 = c * CS;
    #pragma unroll
    for (int tt = 0; tt < CS; ++tt) {
        const int t = t0 + tt;
        const uint2* tp = (const uint2*)((const unsigned short*)Tb + (size_t)t * J_ + p * 12);
        uint2 u0 = tp[0], u1 = tp[1], u2 = tp[2];
        float T0[6] = { bl_(u0.x), bh_(u0.x), bl_(u0.y), bh_(u0.y), bl_(u1.x), bh_(u1.x) };
        float T1[6] = { bl_(u1.y), bh_(u1.y), bl_(u2.x), bh_(u2.x), bl_(u2.y), bh_(u2.y) };
        float sT0[6];
        #pragma unroll
        for (int l = 0; l < 6; ++l) sT0[l] = SLS * T0[l];

        #pragma unroll
        for (int j = 0; j < 7; ++j) {
            float m[6];
            m[0] = hc[j][0] * sT0[0];
            #pragma unroll
            for (int i = 1; i < 6; ++i)
                m[i] = fmaf(hc[j][i - 1], T1[i - 1], hc[j][i] * sT0[i]);
            hc[j][0] = m[0] + ((j == 6) ? 1.0f : 0.0f);
            #pragma unroll
            for (int i = 1; i < 6; ++i)
                hc[j][i] = fmaf(m[i - 1], ep[i - 1], m[i]);
            sc[j] += hc[j][5];
        }
    }

    #pragma unroll
    for (int j = 0; j < 7; ++j) {
        #pragma unroll
        for (int i = 0; i < 6; ++i)
            G[((size_t)c * 49 + j * 7 + i) * P_ + p] = hc[j][i];
        G[((size_t)c * 49 + j * 7 + 6) * P_ + p] = sc[j];
    }
}

// ---------------------------------------------------------------------------
// Kernel 3: generic compose level — compose 8 consecutive maps.
// grid = (nsrc/8)*4 blocks x 64 threads.
// ---------------------------------------------------------------------------
__global__ __launch_bounds__(64) void compose_lvl(
    const float* __restrict__ S, float* __restrict__ Dst)
{
    const int g = blockIdx.x >> 2;
    const int p = (blockIdx.x & 3) * 64 + threadIdx.x;

    float Rh[7][6], Rs[7];
    #pragma unroll
    for (int j = 0; j < 7; ++j) {
        Rs[j] = 0.0f;
        #pragma unroll
        for (int i = 0; i < 6; ++i) Rh[j][i] = (i == j) ? 1.0f : 0.0f;
    }

    for (int cc = 0; cc < 8; ++cc) {
        const int c = g * 8 + cc;
        float Ch[7][6], Csv[7];
        #pragma unroll
        for (int j = 0; j < 7; ++j) {
            #pragma unroll
            for (int i = 0; i < 6; ++i)
                Ch[j][i] = S[((size_t)c * 49 + j * 7 + i) * P_ + p];
            Csv[j] = S[((size_t)c * 49 + j * 7 + 6) * P_ + p];
        }
        float Nh[7][6], Ns[7];
        #pragma unroll
        for (int j = 0; j < 7; ++j) {
            #pragma unroll
            for (int i = 0; i < 6; ++i) {
                float a = (j == 6) ? Ch[6][i] : 0.0f;
                #pragma unroll
                for (int u = 0; u < 6; ++u) a = fmaf(Ch[u][i], Rh[j][u], a);
                Nh[j][i] = a;
            }
            float sa = Rs[j] + ((j == 6) ? Csv[6] : 0.0f);
            #pragma unroll
            for (int u = 0; u < 6; ++u) sa = fmaf(Csv[u], Rh[j][u], sa);
            Ns[j] = sa;
        }
        #pragma unroll
        for (int j = 0; j < 7; ++j) {
            Rs[j] = Ns[j];
            #pragma unroll
            for (int i = 0; i < 6; ++i) Rh[j][i] = Nh[j][i];
        }
    }

    #pragma unroll
    for (int j = 0; j < 7; ++j) {
        #pragma unroll
        for (int i = 0; i < 6; ++i)
            Dst[((size_t)g * 49 + j * 7 + i) * P_ + p] = Rh[j][i];
        Dst[((size_t)g * 49 + j * 7 + 6) * P_ + p] = Rs[j];
    }
}

// ---------------------------------------------------------------------------
// Kernel 4 (fused): apply NL2=8 maps to (h0,0) -> scores, then the MLP head.
// Single block, 256 threads; G3 reads are p-coalesced.
// ---------------------------------------------------------------------------
__global__ __launch_bounds__(256) void l2_mlp(
    const float* __restrict__ G3,
    const float* __restrict__ w0, const float* __restrict__ b0,
    const float* __restrict__ w1, const float* __restrict__ b1,
    const float* __restrict__ w2, const float* __restrict__ b2,
    float* __restrict__ out)
{
    __shared__ float s0[H_], z0[H_], z1[H_];
    const int p = threadIdx.x;

    float h[6] = {1.0f, 0.0f, 0.0f, 0.0f, 0.0f, 0.0f};
    float s = 0.0f;
    for (int g = 0; g < NL2; ++g) {
        float Ch[7][6], Csv[7];
        #pragma unroll
        for (int j = 0; j < 7; ++j) {
            #pragma unroll
            for (int i = 0; i < 6; ++i)
                Ch[j][i] = G3[((size_t)g * 49 + j * 7 + i) * P_ + p];
            Csv[j] = G3[((size_t)g * 49 + j * 7 + 6) * P_ + p];
        }
        float nh[6];
        #pragma unroll
        for (int i = 0; i < 6; ++i) {
            float a = Ch[6][i];
            #pragma unroll
            for (int u = 0; u < 6; ++u) a = fmaf(Ch[u][i], h[u], a);
            nh[i] = a;
        }
        float ns = s + Csv[6];
        #pragma unroll
        for (int u = 0; u < 6; ++u) ns = fmaf(Csv[u], h[u], ns);
        #pragma unroll
        for (int i = 0; i < 6; ++i) h[i] = nh[i];
        s = ns;
    }
    s0[p] = s;
    __syncthreads();

    float acc = b0[p];
    {
        const float4* wr = (const float4*)(w0 + (size_t)p * P_);
        #pragma unroll 4
        for (int q = 0; q < P_ / 4; ++q) {
            float4 w = wr[q];
            acc = fmaf(w.x, s0[q * 4 + 0], acc);
            acc = fmaf(w.y, s0[q * 4 + 1], acc);
            acc = fmaf(w.z, s0[q * 4 + 2], acc);
            acc = fmaf(w.w, s0[q * 4 + 3], acc);
        }
    }
    z0[p] = fmaxf(acc, 0.0f);
    __syncthreads();

    acc = b1[p];
    {
        const float4* wr = (const float4*)(w1 + (size_t)p * H_);
        #pragma unroll 4
        for (int q = 0; q < H_ / 4; ++q) {
            float4 w = wr[q];
            acc = fmaf(w.x, z0[q * 4 + 0], acc);
            acc = fmaf(w.y, z0[q * 4 + 1], acc);
            acc = fmaf(w.z, z0[q * 4 + 2], acc);
            acc = fmaf(w.w, z0[q * 4 + 3], acc);
        }
    }
    z1[p] = fmaxf(acc, 0.0f);
    __syncthreads();

    if (p < C_) {
        float o = b2[p];
        const float* wr = w2 + (size_t)p * H_;
        for (int hh = 0; hh < H_; ++hh) o = fmaf(wr[hh], z1[hh], o);
        out[p] = o;
    }
}

// ---------------------------------------------------------------------------
extern "C" void kernel_launch(void* const* d_in, const int* in_sizes, int n_in,
                              void* d_out, int out_size, void* d_ws, size_t ws_size,
                              hipStream_t stream)
{
    const int*   doc     = (const int*)d_in[0];
    const float* emb     = (const float*)d_in[1];
    const float* diags   = (const float*)d_in[2];
    const float* bias    = (const float*)d_in[3];
    const float* epsilon = (const float*)d_in[4];
    const float* w0      = (const float*)d_in[5];
    const float* b0      = (const float*)d_in[6];
    const float* w1      = (const float*)d_in[7];
    const float* b1      = (const float*)d_in[8];
    const float* w2      = (const float*)d_in[9];
    const float* b2      = (const float*)d_in[10];
    float* out = (float*)d_out;

    // Workspace (~59 MB): fp32 first, then bf16 (keeps 16B alignment for X/Bb).
    float* G      = (float*)d_ws;                          // 512*49*256   (25.7 MB)
    float* G2     = G  + (size_t)NCH * 49 * P_;            // 64*49*256    ( 3.2 MB)
    float* G3     = G2 + (size_t)NL1 * 49 * P_;            // 8*49*256     ( 0.4 MB)
    float* scores_end = G3 + (size_t)NL2 * 49 * P_ + P_;   // (unused pad for alignment)
    __hip_bfloat16* Tb = (__hip_bfloat16*)scores_end;      // N_*J_ bf16   (25.2 MB)
    __hip_bfloat16* X  = Tb + (size_t)N_ * J_;             // N_*KP bf16   ( 2.6 MB)
    __hip_bfloat16* Bb = X  + (size_t)N_ * KP;             // J_*KP bf16   ( 2.0 MB)

    prep_XB<<<(N_ * KP + J_ * KP) / 256, 256, 0, stream>>>(doc, emb, diags, X, Bb);
    gemm_mfma<<<(J_ / 128) * (N_ / 128), 256, 0, stream>>>(X, Bb, bias, Tb);
    scan_pass1<<<NCH, 256, 0, stream>>>(Tb, epsilon, G);
    compose_lvl<<<(NCH / 8) * 4, 64, 0, stream>>>(G, G2);    // 512 -> 64
    compose_lvl<<<(NL1 / 8) * 4, 64, 0, stream>>>(G2, G3);   // 64  -> 8
    l2_mlp<<<1, 256, 0, stream>>>(G3, w0, b0, w1, b1, w2, b2, out);
}